// Round 6
// baseline (317.102 us; speedup 1.0000x reference)
//
#include <hip/hip_runtime.h>
#include <hip/hip_bf16.h>
#include <math.h>

#define B_  2048
#define E_  64
#define H_  512
#define T_  20

typedef _Float16 half8 __attribute__((ext_vector_type(8)));
typedef __attribute__((ext_vector_type(4))) float f32x4;

#define mf16(a, b, c) __builtin_amdgcn_mfma_f32_16x16x32_f16(a, b, c, 0, 0, 0)

__device__ __forceinline__ float sigmoidf_(float x) {
  return 1.0f / (1.0f + __expf(-x));
}
__device__ __forceinline__ float tanh_fast(float x) {
  float e = __expf(2.0f * x);
  return 1.0f - 2.0f / (e + 1.0f);
}
__device__ __forceinline__ void glds16(const _Float16* src, _Float16* dst) {
  __builtin_amdgcn_global_load_lds(
      (const __attribute__((address_space(1))) unsigned int*)src,
      (__attribute__((address_space(3))) unsigned int*)dst, 16, 0, 0);
}

// ---------------------------------------------------------------------------
// Parallel stable counting sort + inverse perm + zero barrier counters.
// perm = stable argsort(-len); iperm[perm[i]] = i; Mt[t] = #(len > t).
// ---------------------------------------------------------------------------
__global__ __launch_bounds__(256) void k_setup(const int* __restrict__ data,
                                               const int* __restrict__ st,
                                               int* __restrict__ perm,
                                               int* __restrict__ iperm,
                                               int* __restrict__ Mt,
                                               int* __restrict__ bar) {
  __shared__ int lens[B_];
  __shared__ int hist[256][22];
  __shared__ int sub[16][22];
  __shared__ int subpre[16][22];
  __shared__ int cnt[32];
  __shared__ int offs[32];
  int tid = threadIdx.x;

  #pragma unroll
  for (int i = 0; i < 4; ++i) bar[tid * 4 + i] = 0;

  #pragma unroll
  for (int q = 0; q < 8; ++q) {
    int i = tid * 8 + q;
    lens[i] = st[data[i] * (T_ + 1) + T_];
  }
  #pragma unroll
  for (int L = 0; L < 22; ++L) hist[tid][L] = 0;
  #pragma unroll
  for (int q = 0; q < 8; ++q) hist[tid][lens[tid * 8 + q]]++;
  __syncthreads();

  for (int q = tid; q < 16 * 21; q += 256) {
    int g = q / 21, L = q % 21;
    int run = 0;
    for (int j = 0; j < 16; ++j) {
      int v = hist[g * 16 + j][L];
      hist[g * 16 + j][L] = run;
      run += v;
    }
    sub[g][L] = run;
  }
  __syncthreads();
  if (tid < 21) {
    int run = 0;
    for (int g = 0; g < 16; ++g) { subpre[g][tid] = run; run += sub[g][tid]; }
    cnt[tid] = run;
  }
  __syncthreads();
  if (tid <= 20) {
    int s = 0;
    for (int L = tid + 1; L <= 20; ++L) s += cnt[L];
    offs[tid] = s;
  }
  __syncthreads();
  if (tid < T_) Mt[tid] = offs[tid];

  int g = tid >> 4;
  #pragma unroll
  for (int q = 0; q < 8; ++q) {
    int i = tid * 8 + q;
    int L = lens[i];
    int rk = subpre[g][L] + hist[tid][L];
    hist[tid][L] += 1;
    perm[offs[L] + rk] = i;
  }
  __syncthreads();
  #pragma unroll
  for (int q = 0; q < 8; ++q) {
    int i = tid * 8 + q;
    iperm[perm[i]] = i;
  }
}

__global__ void k_schars(const int* __restrict__ data, const int* __restrict__ st,
                         const int* __restrict__ perm, int* __restrict__ schars_T) {
  int idx = blockIdx.x * 256 + threadIdx.x;
  if (idx >= B_ * T_) return;
  int t = idx >> 11;
  int j = idx & (B_ - 1);
  schars_T[idx] = st[data[perm[j]] * (T_ + 1) + t];
}

// W -> fp16 fragment-packed: Wp[(((cb*18+c)*4+w)*3+g)*512 + l*8 + e]
// lane l, wave w, colblock cb: gaterow g*512+cb*64+w*16+(l&15), k c*32+(l>>4)*8+e
__global__ void k_wconv(const float* __restrict__ W_ih, const float* __restrict__ W_hh,
                        _Float16* __restrict__ Wp) {
  int idx = blockIdx.x * 256 + threadIdx.x;
  if (idx >= 8 * 18 * 12 * 512) return;
  int e = idx & 7;
  int l = (idx >> 3) & 63;
  int rest = idx >> 9;
  int g = rest % 3;  rest /= 3;
  int w = rest & 3;  rest >>= 2;
  int c = rest % 18;
  int cb = rest / 18;
  int grow = g * H_ + cb * 64 + w * 16 + (l & 15);
  int k = c * 32 + (l >> 4) * 8 + e;
  float v = (k < E_) ? W_ih[grow * E_ + k] : W_hh[grow * H_ + (k - E_)];
  Wp[idx] = (_Float16)v;
}

__global__ void k_embconv(const float* __restrict__ emb, _Float16* __restrict__ embp) {
  int idx = blockIdx.x * 256 + threadIdx.x;
  if (idx >= 128 * E_) return;
  embp[idx] = (_Float16)emb[idx];
}

// ---------------------------------------------------------------------------
// Persistent GRU: all 20 steps in one kernel. Plain launch, 256 blocks x 256
// thr, __launch_bounds__(256,1) -> 1 block/CU -> all 256 co-resident.
// rb = bid&31 (64-row stripe), cb = bid>>5 (64 hcols). W frags in 216 VGPRs.
// fp32 h state in 16 VGPRs/thread. Per-rb 8-block barrier between steps
// (release fence + agent atomic; spin + acquire fence). h exchanged via fp16
// ping-pong buffers. h staged to LDS via global_load_lds with XOR swizzle
// (pre-swizzled per-lane global src, swizzled ds_read offset). emb fragments
// loaded per-lane directly from the 16KB L1-resident packed table.
// ---------------------------------------------------------------------------
__global__ __launch_bounds__(256, 1) void k_gru(
    const int* __restrict__ Mt, const int* __restrict__ schars_T,
    const _Float16* __restrict__ embp, const _Float16* __restrict__ Wp,
    const float* __restrict__ b_ih, const float* __restrict__ b_hh,
    _Float16* __restrict__ hq0, _Float16* __restrict__ hq1,
    const int* __restrict__ iperm, float* __restrict__ out,
    int* __restrict__ bar) {
  __shared__ __attribute__((aligned(16))) _Float16 As[64][512];   // 64 KB

  int bid = blockIdx.x;
  int rb = bid & 31, cb = bid >> 5;
  int m0 = rb * 64;
  int tid = threadIdx.x;
  int w = tid >> 6;
  int l = tid & 63;
  int ln = l & 15, kc = l >> 4;

  // ---- W fragments -> registers (persist across all steps) ----
  half8 wfr[54];
  const _Float16* wsrc = Wp + ((size_t)(cb * 18) * 12 + w * 3) * 512 + l * 8;
  #pragma unroll
  for (int c = 0; c < 18; ++c) {
    #pragma unroll
    for (int g = 0; g < 3; ++g)
      wfr[c * 3 + g] = *(const half8*)(wsrc + (c * 12 + g) * 512);
  }

  int colg = cb * 64 + w * 16 + ln;
  float br  = b_ih[colg] + b_hh[colg];
  float bz  = b_ih[H_ + colg] + b_hh[H_ + colg];
  float bnx = b_ih[2 * H_ + colg];
  float bnh = b_hh[2 * H_ + colg];

  float hreg[4][4];
  #pragma unroll
  for (int i = 0; i < 4; ++i)
    #pragma unroll
    for (int j = 0; j < 4; ++j) hreg[i][j] = 0.0f;

  int* barp = bar + rb * 32;

  for (int t = 0; t < T_; ++t) {
    int M = Mt[t];
    if (m0 >= M) break;
    const _Float16* hin = (t & 1) ? hq1 : hq0;
    _Float16*       hout = (t & 1) ? hq0 : hq1;

    if (t > 0) {
      if (tid == 0) {
        int target = 8 * t;
        while (__hip_atomic_load(barp, __ATOMIC_RELAXED, __HIP_MEMORY_SCOPE_AGENT) < target)
          __builtin_amdgcn_s_sleep(1);
      }
      __syncthreads();
      __builtin_amdgcn_fence(__ATOMIC_ACQUIRE, "agent");
      __builtin_amdgcn_sched_barrier(0);
      // stage h rows [w*16, w*16+16); one glds16 = one full 1KB row
      #pragma unroll
      for (int i = 0; i < 16; ++i) {
        int r = w * 16 + i;
        const _Float16* src = hin + (size_t)(m0 + r) * H_ + ((l ^ (i & 7)) << 3);
        glds16(src, &As[r][0]);
      }
    }

    f32x4 accr[4], accz[4], accnx[4], accnh[4];
    #pragma unroll
    for (int i = 0; i < 4; ++i) {
      accr[i] = (f32x4){0.f, 0.f, 0.f, 0.f};
      accz[i] = (f32x4){0.f, 0.f, 0.f, 0.f};
      accnx[i] = (f32x4){0.f, 0.f, 0.f, 0.f};
      accnh[i] = (f32x4){0.f, 0.f, 0.f, 0.f};
    }

    // ---- emb chunks (k=0..64): per-lane fragment loads, overlap staging ----
    #pragma unroll
    for (int rf = 0; rf < 4; ++rf) {
      int ch = schars_T[t * B_ + m0 + rf * 16 + ln];
      const _Float16* ep = embp + ch * E_ + kc * 8;
      half8 a0 = *(const half8*)ep;
      half8 a1 = *(const half8*)(ep + 32);
      accr[rf]  = mf16(a0, wfr[0], accr[rf]);
      accz[rf]  = mf16(a0, wfr[1], accz[rf]);
      accnx[rf] = mf16(a0, wfr[2], accnx[rf]);
      accr[rf]  = mf16(a1, wfr[3], accr[rf]);
      accz[rf]  = mf16(a1, wfr[4], accz[rf]);
      accnx[rf] = mf16(a1, wfr[5], accnx[rf]);
    }

    __syncthreads();   // staging complete (drains vmcnt); block-wide sync

    if (t > 0) {
      const _Float16* asb = &As[0][0];
      #pragma unroll
      for (int ch = 0; ch < 16; ++ch) {
        #pragma unroll
        for (int rf = 0; rf < 4; ++rf) {
          int r = rf * 16 + ln;
          half8 af = *(const half8*)(asb + r * 512 + (((ch * 4 + kc) ^ (ln & 7)) << 3));
          accr[rf]  = mf16(af, wfr[(ch + 2) * 3 + 0], accr[rf]);
          accz[rf]  = mf16(af, wfr[(ch + 2) * 3 + 1], accz[rf]);
          accnh[rf] = mf16(af, wfr[(ch + 2) * 3 + 2], accnh[rf]);
        }
      }
    }

    // ---- epilogue: gates, fp32 reg state, fp16 h-out for partners ----
    #pragma unroll
    for (int rf = 0; rf < 4; ++rf) {
      #pragma unroll
      for (int q = 0; q < 4; ++q) {
        int row = m0 + rf * 16 + kc * 4 + q;
        if (row < M) {
          float r_ = sigmoidf_(accr[rf][q] + br);
          float z_ = sigmoidf_(accz[rf][q] + bz);
          float n_ = tanh_fast(accnx[rf][q] + bnx + r_ * (accnh[rf][q] + bnh));
          float hnew = (1.0f - z_) * n_ + z_ * hreg[rf][q];
          hreg[rf][q] = hnew;
          hout[(size_t)row * H_ + colg] = (_Float16)hnew;
        }
      }
    }
    __syncthreads();               // all waves' stores drained (vmcnt 0)
    if (tid == 0) {
      __builtin_amdgcn_fence(__ATOMIC_RELEASE, "agent");
      __hip_atomic_fetch_add(barp, 1, __ATOMIC_RELAXED, __HIP_MEMORY_SCOPE_AGENT);
    }
  }

  // ---- final state -> out[iperm[row]] (reference returns ht[perm]) ----
  #pragma unroll
  for (int rf = 0; rf < 4; ++rf) {
    #pragma unroll
    for (int q = 0; q < 4; ++q) {
      int row = m0 + rf * 16 + kc * 4 + q;
      out[(size_t)iperm[row] * H_ + colg] = hreg[rf][q];
    }
  }
}

extern "C" void kernel_launch(void* const* d_in, const int* in_sizes, int n_in,
                              void* d_out, int out_size, void* d_ws, size_t ws_size,
                              hipStream_t stream) {
  const int*   data = (const int*)d_in[0];
  const int*   st   = (const int*)d_in[1];
  const float* emb  = (const float*)d_in[2];
  const float* W_ih = (const float*)d_in[3];
  const float* W_hh = (const float*)d_in[4];
  const float* b_ih = (const float*)d_in[5];
  const float* b_hh = (const float*)d_in[6];
  float* out = (float*)d_out;

  // workspace (~6 MB)
  _Float16* hq0  = (_Float16*)d_ws;                 // B*H fp16
  _Float16* hq1  = hq0 + B_ * H_;                   // B*H fp16
  _Float16* Wp   = hq1 + B_ * H_;                   // 884736 fp16
  _Float16* embp = Wp + 8 * 18 * 12 * 512;          // 128*E fp16
  int* perm   = (int*)(embp + 128 * E_);
  int* iperm  = perm + B_;
  int* Mt     = iperm + B_;
  int* bar    = Mt + 32;                            // 32 rb * 32 stride
  int* schars = bar + 32 * 32;

  k_setup<<<1, 256, 0, stream>>>(data, st, perm, iperm, Mt, bar);
  k_schars<<<(B_ * T_ + 255) / 256, 256, 0, stream>>>(data, st, perm, schars);
  k_wconv<<<(8 * 18 * 12 * 512 + 255) / 256, 256, 0, stream>>>(W_ih, W_hh, Wp);
  k_embconv<<<(128 * E_ + 255) / 256, 256, 0, stream>>>(emb, embp);

  k_gru<<<dim3(256), dim3(256), 0, stream>>>(Mt, schars, embp, Wp, b_ih, b_hh,
                                             hq0, hq1, iperm, out, bar);
}

// Round 7
// 186.496 us; speedup vs baseline: 1.7003x; 1.7003x over previous
//
#include <hip/hip_runtime.h>
#include <hip/hip_bf16.h>
#include <math.h>

#define B_  2048
#define E_  64
#define H_  512
#define T_  20

typedef _Float16 half8 __attribute__((ext_vector_type(8)));
typedef __attribute__((ext_vector_type(4))) float f32x4;
typedef unsigned long long u64;

#define mf16(a, b, c) __builtin_amdgcn_mfma_f32_16x16x32_f16(a, b, c, 0, 0, 0)

__device__ __forceinline__ float sigmoidf_(float x) {
  return 1.0f / (1.0f + __expf(-x));
}
__device__ __forceinline__ float tanh_fast(float x) {
  float e = __expf(2.0f * x);
  return 1.0f - 2.0f / (e + 1.0f);
}

// ---------------------------------------------------------------------------
// Parallel stable counting sort + inverse perm + zero barrier counters.
// ---------------------------------------------------------------------------
__global__ __launch_bounds__(256) void k_setup(const int* __restrict__ data,
                                               const int* __restrict__ st,
                                               int* __restrict__ perm,
                                               int* __restrict__ iperm,
                                               int* __restrict__ Mt,
                                               int* __restrict__ bar) {
  __shared__ int lens[B_];
  __shared__ int hist[256][22];
  __shared__ int sub[16][22];
  __shared__ int subpre[16][22];
  __shared__ int cnt[32];
  __shared__ int offs[32];
  int tid = threadIdx.x;

  #pragma unroll
  for (int i = 0; i < 4; ++i) bar[tid * 4 + i] = 0;

  #pragma unroll
  for (int q = 0; q < 8; ++q) {
    int i = tid * 8 + q;
    lens[i] = st[data[i] * (T_ + 1) + T_];
  }
  #pragma unroll
  for (int L = 0; L < 22; ++L) hist[tid][L] = 0;
  #pragma unroll
  for (int q = 0; q < 8; ++q) hist[tid][lens[tid * 8 + q]]++;
  __syncthreads();

  for (int q = tid; q < 16 * 21; q += 256) {
    int g = q / 21, L = q % 21;
    int run = 0;
    for (int j = 0; j < 16; ++j) {
      int v = hist[g * 16 + j][L];
      hist[g * 16 + j][L] = run;
      run += v;
    }
    sub[g][L] = run;
  }
  __syncthreads();
  if (tid < 21) {
    int run = 0;
    for (int g = 0; g < 16; ++g) { subpre[g][tid] = run; run += sub[g][tid]; }
    cnt[tid] = run;
  }
  __syncthreads();
  if (tid <= 20) {
    int s = 0;
    for (int L = tid + 1; L <= 20; ++L) s += cnt[L];
    offs[tid] = s;
  }
  __syncthreads();
  if (tid < T_) Mt[tid] = offs[tid];

  int g = tid >> 4;
  #pragma unroll
  for (int q = 0; q < 8; ++q) {
    int i = tid * 8 + q;
    int L = lens[i];
    int rk = subpre[g][L] + hist[tid][L];
    hist[tid][L] += 1;
    perm[offs[L] + rk] = i;
  }
  __syncthreads();
  #pragma unroll
  for (int q = 0; q < 8; ++q) {
    int i = tid * 8 + q;
    iperm[perm[i]] = i;
  }
}

__global__ void k_schars(const int* __restrict__ data, const int* __restrict__ st,
                         const int* __restrict__ perm, int* __restrict__ schars_T) {
  int idx = blockIdx.x * 256 + threadIdx.x;
  if (idx >= B_ * T_) return;
  int t = idx >> 11;
  int j = idx & (B_ - 1);
  schars_T[idx] = st[data[perm[j]] * (T_ + 1) + t];
}

// W -> fp16 fragment-packed: Wp[(((cb*18+c)*4+w)*3+g)*512 + l*8 + e]
__global__ void k_wconv(const float* __restrict__ W_ih, const float* __restrict__ W_hh,
                        _Float16* __restrict__ Wp) {
  int idx = blockIdx.x * 256 + threadIdx.x;
  if (idx >= 8 * 18 * 12 * 512) return;
  int e = idx & 7;
  int l = (idx >> 3) & 63;
  int rest = idx >> 9;
  int g = rest % 3;  rest /= 3;
  int w = rest & 3;  rest >>= 2;
  int c = rest % 18;
  int cb = rest / 18;
  int grow = g * H_ + cb * 64 + w * 16 + (l & 15);
  int k = c * 32 + (l >> 4) * 8 + e;
  float v = (k < E_) ? W_ih[grow * E_ + k] : W_hh[grow * H_ + (k - E_)];
  Wp[idx] = (_Float16)v;
}

__global__ void k_embconv(const float* __restrict__ emb, _Float16* __restrict__ embp) {
  int idx = blockIdx.x * 256 + threadIdx.x;
  if (idx >= 128 * E_) return;
  embp[idx] = (_Float16)emb[idx];
}

// ---------------------------------------------------------------------------
// Persistent GRU, fence-free coherence:
//  - h-out stores:  __hip_atomic_store RELAXED/AGENT  (global_store sc0 sc1,
//    write-through past the XCD L2 -> no buffer_wbl2 needed)
//  - h staging:     __hip_atomic_load RELAXED/AGENT u64 (global_load sc1,
//    bypasses stale L1/L2 -> no buffer_inv needed), then swizzled ds_write
//  - step barrier:  __syncthreads (drains vmcnt) + relaxed agent atomicAdd;
//    reader spins on relaxed agent load.
// W fragments persist in 216 VGPRs; fp32 h state in 16 VGPRs/thread.
// ---------------------------------------------------------------------------
__global__ __launch_bounds__(256, 1) void k_gru(
    const int* __restrict__ Mt, const int* __restrict__ schars_T,
    const _Float16* __restrict__ embp, const _Float16* __restrict__ Wp,
    const float* __restrict__ b_ih, const float* __restrict__ b_hh,
    _Float16* __restrict__ hq0, _Float16* __restrict__ hq1,
    const int* __restrict__ iperm, float* __restrict__ out,
    int* __restrict__ bar) {
  __shared__ __attribute__((aligned(16))) _Float16 As[64][512];   // 64 KB

  int bid = blockIdx.x;
  int rb = bid & 31, cb = bid >> 5;
  int m0 = rb * 64;
  int tid = threadIdx.x;
  int w = tid >> 6;
  int l = tid & 63;
  int ln = l & 15, kc = l >> 4;

  // ---- W fragments -> registers (persist across all steps) ----
  half8 wfr[54];
  const _Float16* wsrc = Wp + ((size_t)(cb * 18) * 12 + w * 3) * 512 + l * 8;
  #pragma unroll
  for (int c = 0; c < 18; ++c) {
    #pragma unroll
    for (int g = 0; g < 3; ++g)
      wfr[c * 3 + g] = *(const half8*)(wsrc + (c * 12 + g) * 512);
  }

  int colg = cb * 64 + w * 16 + ln;
  float br  = b_ih[colg] + b_hh[colg];
  float bz  = b_ih[H_ + colg] + b_hh[H_ + colg];
  float bnx = b_ih[2 * H_ + colg];
  float bnh = b_hh[2 * H_ + colg];

  float hreg[4][4];
  #pragma unroll
  for (int i = 0; i < 4; ++i)
    #pragma unroll
    for (int j = 0; j < 4; ++j) hreg[i][j] = 0.0f;

  int* barp = bar + rb * 32;

  for (int t = 0; t < T_; ++t) {
    int M = Mt[t];
    if (m0 >= M) break;
    const _Float16* hin = (t & 1) ? hq1 : hq0;
    _Float16*       hout = (t & 1) ? hq0 : hq1;

    u64 sb[16][2];
    if (t > 0) {
      if (tid == 0) {
        int target = 8 * t;
        while (__hip_atomic_load(barp, __ATOMIC_RELAXED, __HIP_MEMORY_SCOPE_AGENT) < target)
          __builtin_amdgcn_s_sleep(1);
      }
      __syncthreads();
      // issue all 16 row-loads (device-scope, bypass stale L2); swizzled src
      #pragma unroll
      for (int i = 0; i < 16; ++i) {
        int r = w * 16 + i;
        u64* src = (u64*)(hin + (size_t)(m0 + r) * H_) + ((l ^ (r & 7)) << 1);
        sb[i][0] = __hip_atomic_load(src, __ATOMIC_RELAXED, __HIP_MEMORY_SCOPE_AGENT);
        sb[i][1] = __hip_atomic_load(src + 1, __ATOMIC_RELAXED, __HIP_MEMORY_SCOPE_AGENT);
      }
    }

    f32x4 accr[4], accz[4], accnx[4], accnh[4];
    #pragma unroll
    for (int i = 0; i < 4; ++i) {
      accr[i] = (f32x4){0.f, 0.f, 0.f, 0.f};
      accz[i] = (f32x4){0.f, 0.f, 0.f, 0.f};
      accnx[i] = (f32x4){0.f, 0.f, 0.f, 0.f};
      accnh[i] = (f32x4){0.f, 0.f, 0.f, 0.f};
    }

    // ---- emb chunks (k=0..64): per-lane fragment loads (L1-resident) ----
    #pragma unroll
    for (int rf = 0; rf < 4; ++rf) {
      int ch = schars_T[t * B_ + m0 + rf * 16 + ln];
      const _Float16* ep = embp + ch * E_ + kc * 8;
      half8 a0 = *(const half8*)ep;
      half8 a1 = *(const half8*)(ep + 32);
      accr[rf]  = mf16(a0, wfr[0], accr[rf]);
      accz[rf]  = mf16(a0, wfr[1], accz[rf]);
      accnx[rf] = mf16(a0, wfr[2], accnx[rf]);
      accr[rf]  = mf16(a1, wfr[3], accr[rf]);
      accz[rf]  = mf16(a1, wfr[4], accz[rf]);
      accnx[rf] = mf16(a1, wfr[5], accnx[rf]);
    }

    if (t > 0) {
      // drain staged rows into LDS (linear dest slot l; src was pre-swizzled)
      #pragma unroll
      for (int i = 0; i < 16; ++i) {
        int r = w * 16 + i;
        u64* dp = (u64*)&As[r][l * 8];
        dp[0] = sb[i][0];
        dp[1] = sb[i][1];
      }
    }
    __syncthreads();

    if (t > 0) {
      const _Float16* asb = &As[0][0];
      #pragma unroll
      for (int ch = 0; ch < 16; ++ch) {
        #pragma unroll
        for (int rf = 0; rf < 4; ++rf) {
          int r = rf * 16 + ln;
          half8 af = *(const half8*)(asb + r * 512 + (((ch * 4 + kc) ^ (ln & 7)) << 3));
          accr[rf]  = mf16(af, wfr[(ch + 2) * 3 + 0], accr[rf]);
          accz[rf]  = mf16(af, wfr[(ch + 2) * 3 + 1], accz[rf]);
          accnh[rf] = mf16(af, wfr[(ch + 2) * 3 + 2], accnh[rf]);
        }
      }
    }

    // ---- epilogue: gates, fp32 reg state, device-scope fp16 h-out ----
    #pragma unroll
    for (int rf = 0; rf < 4; ++rf) {
      #pragma unroll
      for (int q = 0; q < 4; ++q) {
        int row = m0 + rf * 16 + kc * 4 + q;
        if (row < M) {
          float r_ = sigmoidf_(accr[rf][q] + br);
          float z_ = sigmoidf_(accz[rf][q] + bz);
          float n_ = tanh_fast(accnx[rf][q] + bnx + r_ * (accnh[rf][q] + bnh));
          float hnew = (1.0f - z_) * n_ + z_ * hreg[rf][q];
          hreg[rf][q] = hnew;
          union { _Float16 f; unsigned short s; } cv;
          cv.f = (_Float16)hnew;
          __hip_atomic_store((unsigned short*)&hout[(size_t)row * H_ + colg], cv.s,
                             __ATOMIC_RELAXED, __HIP_MEMORY_SCOPE_AGENT);
        }
      }
    }
    __syncthreads();               // drains vmcnt for all waves -> stores visible
    if (tid == 0) {
      __hip_atomic_fetch_add(barp, 1, __ATOMIC_RELAXED, __HIP_MEMORY_SCOPE_AGENT);
    }
  }

  // ---- final state -> out[iperm[row]] (reference returns ht[perm]) ----
  #pragma unroll
  for (int rf = 0; rf < 4; ++rf) {
    #pragma unroll
    for (int q = 0; q < 4; ++q) {
      int row = m0 + rf * 16 + kc * 4 + q;
      out[(size_t)iperm[row] * H_ + colg] = hreg[rf][q];
    }
  }
}

extern "C" void kernel_launch(void* const* d_in, const int* in_sizes, int n_in,
                              void* d_out, int out_size, void* d_ws, size_t ws_size,
                              hipStream_t stream) {
  const int*   data = (const int*)d_in[0];
  const int*   st   = (const int*)d_in[1];
  const float* emb  = (const float*)d_in[2];
  const float* W_ih = (const float*)d_in[3];
  const float* W_hh = (const float*)d_in[4];
  const float* b_ih = (const float*)d_in[5];
  const float* b_hh = (const float*)d_in[6];
  float* out = (float*)d_out;

  // workspace (~6 MB)
  _Float16* hq0  = (_Float16*)d_ws;                 // B*H fp16
  _Float16* hq1  = hq0 + B_ * H_;                   // B*H fp16
  _Float16* Wp   = hq1 + B_ * H_;                   // 884736 fp16
  _Float16* embp = Wp + 8 * 18 * 12 * 512;          // 128*E fp16
  int* perm   = (int*)(embp + 128 * E_);
  int* iperm  = perm + B_;
  int* Mt     = iperm + B_;
  int* bar    = Mt + 32;                            // 32 rb * 32 stride
  int* schars = bar + 32 * 32;

  k_setup<<<1, 256, 0, stream>>>(data, st, perm, iperm, Mt, bar);
  k_schars<<<(B_ * T_ + 255) / 256, 256, 0, stream>>>(data, st, perm, schars);
  k_wconv<<<(8 * 18 * 12 * 512 + 255) / 256, 256, 0, stream>>>(W_ih, W_hh, Wp);
  k_embconv<<<(128 * E_ + 255) / 256, 256, 0, stream>>>(emb, embp);

  k_gru<<<dim3(256), dim3(256), 0, stream>>>(Mt, schars, embp, Wp, b_ih, b_hh,
                                             hq0, hq1, iperm, out, bar);
}